// Round 9
// baseline (78.751 us; speedup 1.0000x reference)
//
#include <hip/hip_runtime.h>
#include <math.h>

// KShape dists via bf16 MFMA. B=256, K=16, SZ=512, D=8.
// corr[b,i,k] = sum_{t,d} xpad[b][(i+t)*8+d] * c[k][t*8+d],  i in [0,1022]
// dists[b,k] = max_i corr / (||x_b|| * k); k=0 -> 0. labels = first argmax.
// out: [0..255]=labels(float), [256..4351]=dists.
//
// R9: 8-tile wave shape at full register budget. 512 blocks x 256 threads
// (launch_bounds(256,2) -> 256-reg cap; Q[32]+acc[8] ~= 200 fits, 2 waves/
// SIMD via 2 blocks/CU). Block=(b,half): 4 waves x 8 row-tiles = 512 lags.
// 1 ds_read_b128 A-refill + 1 B-read feed 8 MFMAs (halves LDS instr/MFMA vs
// R8). Trapezoid windows 16-aligned; B double-buffered in LDS (16-kc chunks)
// with parity-templated bodies so all ring indices stay compile-time (no R5
// spill trigger). Per-CU: 688 kc-iters, LDS ~6.9us floor, MFMA ~2.9us.

#define NB 256
#define NK 16
#define NS 512
#define ND 8

typedef __bf16 bf16x8 __attribute__((ext_vector_type(8)));
typedef float floatx4 __attribute__((ext_vector_type(4)));

// ---- pack centers into B-fragment order ----
// Bpk[kc*64 + L][0..8) = bf16( c[n = L&15][ (kc*4 + (L>>4))*8 + j ] )  j=0..7
__global__ void pack_kernel(const float* __restrict__ c, __bf16* __restrict__ bpk)
{
    int kc = blockIdx.x;      // 0..127
    int L  = threadIdx.x;     // 0..63
    int n = L & 15, quad = L >> 4;
    const float4* src = (const float4*)(c + ((size_t)n * NS + (size_t)(kc * 4 + quad)) * ND);
    float4 a = src[0], b = src[1];
    bf16x8 v;
    v[0] = (__bf16)a.x; v[1] = (__bf16)a.y; v[2] = (__bf16)a.z; v[3] = (__bf16)a.w;
    v[4] = (__bf16)b.x; v[5] = (__bf16)b.y; v[6] = (__bf16)b.z; v[7] = (__bf16)b.w;
    *(bf16x8*)(bpk + ((size_t)kc * 64 + L) * 8) = v;
}

#define MFMA(q, bv, a) __builtin_amdgcn_mfma_f32_16x16x32_bf16(q, bv, a, 0, 0, 0)

// one 16-kc chunk; P = 16*(ch&1) keeps ring indices compile-time
template <int P>
__device__ __forceinline__ void chunk_body(bf16x8 (&Q)[32], floatx4 (&acc)[8],
                                           const __bf16* gb, const __bf16* bls,
                                           int L, int ch)
{
    const __bf16* bb = bls + L * 8;
    bf16x8 b0 = *(const bf16x8*)(bb);
    bf16x8 b1 = *(const bf16x8*)(bb + 512);
    #pragma unroll
    for (int s = 0; s < 16; ++s) {
        bf16x8 bcur = (s & 1) ? b1 : b0;
        acc[0] = MFMA(Q[(P + s +  0) & 31], bcur, acc[0]);
        acc[1] = MFMA(Q[(P + s +  4) & 31], bcur, acc[1]);
        acc[2] = MFMA(Q[(P + s +  8) & 31], bcur, acc[2]);
        acc[3] = MFMA(Q[(P + s + 12) & 31], bcur, acc[3]);
        acc[4] = MFMA(Q[(P + s + 16) & 31], bcur, acc[4]);
        acc[5] = MFMA(Q[(P + s + 20) & 31], bcur, acc[5]);
        acc[6] = MFMA(Q[(P + s + 24) & 31], bcur, acc[6]);
        acc[7] = MFMA(Q[(P + s + 28) & 31], bcur, acc[7]);
        // slot (P+s)&31 dead after acc[0]; refill with row4 = 16ch + s + 32
        Q[(P + s) & 31] = *(const bf16x8*)(gb + 32 * (16 * ch + s + 32));
        if (s < 14) {
            bf16x8 nb = *(const bf16x8*)(bb + (s + 2) * 512);
            if (s & 1) b1 = nb; else b0 = nb;
        }
    }
}

// ---- main: block = (b, half); 4 waves x 8 row-tiles = 512 lag rows ----
__global__ __launch_bounds__(256, 2) void dists_mfma(
    const float* __restrict__ x, const __bf16* __restrict__ bpk,
    float* __restrict__ wsfm, float* __restrict__ wsfn)
{
    __shared__ __align__(16) __bf16 xq[1040 * 8];       // 16.25 KB (h=0 needs 1040 rows)
    __shared__ __align__(16) __bf16 Bls[2][16 * 512];   // 32 KB double buffer
    __shared__ float wred[4][16];
    __shared__ float redn[4];

    const int tid = threadIdx.x;
    const int b   = blockIdx.x & 255;
    const int h   = blockIdx.x >> 8;
    const int base = h * 512;
    const int rows = h ? 656 : 1040;   // h=1 band: [512,1168); h=0: [0,1040)

    // stage padded x band (bf16) + sum of squares (f32, h=0 covers all of x)
    float ss = 0.f;
    for (int jj = tid; jj < rows; jj += 256) {
        int j = base + jj;
        bf16x8 v;
        if (j >= 511 && j < 1023) {
            const float4* p = (const float4*)(x + ((size_t)b * NS + (size_t)(j - 511)) * ND);
            float4 a = p[0], bb = p[1];
            ss += a.x * a.x + a.y * a.y + a.z * a.z + a.w * a.w;
            ss += bb.x * bb.x + bb.y * bb.y + bb.z * bb.z + bb.w * bb.w;
            v[0] = (__bf16)a.x;  v[1] = (__bf16)a.y;  v[2] = (__bf16)a.z;  v[3] = (__bf16)a.w;
            v[4] = (__bf16)bb.x; v[5] = (__bf16)bb.y; v[6] = (__bf16)bb.z; v[7] = (__bf16)bb.w;
        } else {
            #pragma unroll
            for (int e = 0; e < 8; ++e) v[e] = (__bf16)0.0f;
        }
        *(bf16x8*)(xq + (size_t)jj * 8) = v;
    }
    // stage B chunk 0 (16 kc = 16 KB = 1024 int4)
    const int4* bsrc = (const int4*)bpk;
    {
        int4* d0 = (int4*)Bls[0];
        #pragma unroll
        for (int i = 0; i < 4; ++i) d0[tid + 256 * i] = bsrc[tid + 256 * i];
    }
    #pragma unroll
    for (int off = 32; off; off >>= 1) ss += __shfl_down(ss, off);
    if ((tid & 63) == 0) redn[tid >> 6] = ss;
    __syncthreads();
    if (h == 0 && tid == 0)
        wsfn[b] = sqrtf(redn[0] + redn[1] + redn[2] + redn[3]);

    const int L    = tid & 63;
    const int m    = L & 15;       // A row within tile / D col (center id)
    const int quad = L >> 4;
    const int wu   = __builtin_amdgcn_readfirstlane(tid >> 6);  // wave 0..3

    // wave-uniform trapezoid window, 16-aligned (block-local rows 128*wu..+128)
    // tile nonzero iff 4kc >= 363-128wu-512h (lower) and 4kc <= 1022-512h-128wu (upper)
    int klo16, khi;
    if (h == 0) {
        int e = (366 - 128 * wu) >> 2;            // exact klo: 91,59,27,<0
        klo16 = (e > 0) ? (e & ~15) : 0;          // 80,48,16,0
        khi = 127;
    } else {
        klo16 = 0;
        khi = (510 - 128 * wu) >> 2;              // 127,95,63,31
    }
    const int chlo = klo16 >> 4, chhi = khi >> 4;

    // A-frag (r,kc): 16B at gb + 32*(4kc... ) ; ring slot (kc+4r)&31
    const __bf16* gb = xq + 8 * (128 * wu + m + quad);

    bf16x8 Q[32];
    if ((chlo & 1) == 0) {
        #pragma unroll
        for (int i = 0; i < 32; ++i) Q[i] = *(const bf16x8*)(gb + 32 * (klo16 + i));
    } else {
        #pragma unroll
        for (int i = 0; i < 32; ++i) Q[(16 + i) & 31] = *(const bf16x8*)(gb + 32 * (klo16 + i));
    }

    floatx4 acc[8] = {};

    for (int ch = 0; ch < 8; ++ch) {
        if (ch < 7) {   // stage next chunk into alternate buffer
            const int4* s4 = bsrc + (size_t)(ch + 1) * 1024;
            int4* d4 = (int4*)Bls[(ch + 1) & 1];
            int4 t0 = s4[tid], t1 = s4[tid + 256], t2 = s4[tid + 512], t3 = s4[tid + 768];
            d4[tid] = t0; d4[tid + 256] = t1; d4[tid + 512] = t2; d4[tid + 768] = t3;
        }
        if (ch >= chlo && ch <= chhi) {
            if ((ch & 1) == 0) chunk_body<0>(Q, acc, gb, Bls[0], L, ch);
            else               chunk_body<16>(Q, acc, gb, Bls[1], L, ch);
        }
        __syncthreads();
    }

    // D layout: col = lane&15 (center), row-in-tile = quad*4 + e.
    // global lag row = 512h + 128wu + 16r + 4quad + e; phantom row 1023 excluded.
    float vmax = -INFINITY;
    #pragma unroll
    for (int r = 0; r < 8; ++r) {
        #pragma unroll
        for (int e = 0; e < 4; ++e) {
            bool phantom = (h == 1) & (wu == 3) & (r == 7) & (quad == 3) & (e == 3);
            vmax = fmaxf(vmax, phantom ? -INFINITY : acc[r][e]);
        }
    }
    vmax = fmaxf(vmax, __shfl_xor(vmax, 16));
    vmax = fmaxf(vmax, __shfl_xor(vmax, 32));
    if (quad == 0) wred[wu][m] = vmax;
    __syncthreads();

    if (tid < 16) {
        float mm = fmaxf(fmaxf(wred[0][tid], wred[1][tid]),
                         fmaxf(wred[2][tid], wred[3][tid]));
        wsfm[(size_t)b * 32 + h * 16 + tid] = mm;
    }
}

// ---- finalize: merge halves, scale, labels ----
__global__ void finalize(const float* __restrict__ wsfm, const float* __restrict__ wsfn,
                         float* __restrict__ out)
{
    __shared__ float dd[16];
    const int b = blockIdx.x, t = threadIdx.x;
    if (t < 16) {
        float mm = fmaxf(wsfm[(size_t)b * 32 + t], wsfm[(size_t)b * 32 + 16 + t]);
        float denom = wsfn[b] * (float)t;
        float d = (denom < 1e-9f) ? 0.f : mm / denom;
        dd[t] = d;
        out[NB + b * NK + t] = d;
    }
    __syncthreads();
    if (t == 0) {
        float best = dd[0]; int lab = 0;
        #pragma unroll
        for (int k = 1; k < NK; ++k) if (dd[k] > best) { best = dd[k]; lab = k; }
        out[b] = (float)lab;
    }
}

extern "C" void kernel_launch(void* const* d_in, const int* in_sizes, int n_in,
                              void* d_out, int out_size, void* d_ws, size_t ws_size,
                              hipStream_t stream) {
    const float* x = (const float*)d_in[0];
    const float* c = (const float*)d_in[1];
    float* out  = (float*)d_out;
    float* wsfm = (float*)d_ws;                        // 256*2*16 floats = 32 KB
    float* wsfn = (float*)((char*)d_ws + 32768);       // 256 floats
    __bf16* bpk = (__bf16*)((char*)d_ws + 65536);      // 128 KB packed B

    pack_kernel<<<128, 64, 0, stream>>>(c, bpk);
    dists_mfma<<<512, 256, 0, stream>>>(x, bpk, wsfm, wsfn);
    finalize<<<NB, 64, 0, stream>>>(wsfm, wsfn, out);
}

// Round 10
// 74.087 us; speedup vs baseline: 1.0630x; 1.0630x over previous
//
#include <hip/hip_runtime.h>
#include <math.h>

// KShape dists via bf16 MFMA. B=256, K=16, SZ=512, D=8.
// corr[b,i,k] = sum_{t,d} xpad[b][(i+t)*8+d] * c[k][t*8+d],  i in [0,1022]
// dists[b,k] = max_i corr / (||x_b|| * k); k=0 -> 0. labels = first argmax.
// out: [0..255]=labels(float), [256..4351]=dists.
//
// R10: SINGLE kernel. 256 blocks x 1024 threads (1 block/CU, 16 waves,
// 4/SIMD -- R8's proven TLP; launch_bounds(1024,4) -> 128-reg cap, Q[16]+
// acc[4] shape fits). Whole packed B (128 KB) + xq band (17.5 KB) resident
// in LDS (~150 KB of the 160 KB/CU): B packed in-kernel from c (L2-resident,
// no pack kernel), ONE barrier total, zero barriers in the main loop.
// B register-FIFO depth 4 (~320cy lookahead > 120cy LDS latency) fixes R8's
// 1-iter bnxt stall. Trapezoid windows per wave (klo=112-16wu, 16-aligned).

#define NB 256
#define NK 16
#define NS 512
#define ND 8
#define BAND 1120   // max A-refill row = 64*15 + 4*(15+16) + 19 = 1103 < 1120

typedef __bf16 bf16x8 __attribute__((ext_vector_type(8)));
typedef float floatx4 __attribute__((ext_vector_type(4)));

#define MFMA(q, bv, a) __builtin_amdgcn_mfma_f32_16x16x32_bf16(q, bv, a, 0, 0, 0)

__global__ __launch_bounds__(1024, 4) void kshape_kernel(
    const float* __restrict__ x, const float* __restrict__ c, float* __restrict__ out)
{
    __shared__ __align__(16) __bf16 xq[BAND * 8];      // 17.5 KB
    __shared__ __align__(16) __bf16 Bf[128 * 512];     // 128 KB: all packed B
    __shared__ float wred[16][16];
    __shared__ float redn[16];
    __shared__ float s_norm;
    __shared__ float dd[16];

    const int tid = threadIdx.x;
    const int b   = blockIdx.x;

    // ---- stage padded x band (bf16) + sum of squares (f32) ----
    float ss = 0.f;
    for (int jj = tid; jj < BAND; jj += 1024) {
        bf16x8 v;
        if (jj >= 511 && jj < 1023) {
            const float4* p = (const float4*)(x + ((size_t)b * NS + (size_t)(jj - 511)) * ND);
            float4 a = p[0], bb = p[1];
            ss += a.x * a.x + a.y * a.y + a.z * a.z + a.w * a.w;
            ss += bb.x * bb.x + bb.y * bb.y + bb.z * bb.z + bb.w * bb.w;
            v[0] = (__bf16)a.x;  v[1] = (__bf16)a.y;  v[2] = (__bf16)a.z;  v[3] = (__bf16)a.w;
            v[4] = (__bf16)bb.x; v[5] = (__bf16)bb.y; v[6] = (__bf16)bb.z; v[7] = (__bf16)bb.w;
        } else {
            #pragma unroll
            for (int e = 0; e < 8; ++e) v[e] = (__bf16)0.0f;
        }
        *(bf16x8*)(xq + (size_t)jj * 8) = v;
    }

    // ---- pack ALL of B into LDS directly from c (fragment order) ----
    // Bf[kc*512 + L*8 + j] = bf16( c[n=L&15][(kc*4 + (L>>4))*8 + j] )
    #pragma unroll 4
    for (int i = 0; i < 8; ++i) {
        int idx = tid + i * 1024;          // (kc,L) fragment id, 0..8191
        int kc = idx >> 6, Lf = idx & 63;
        int n = Lf & 15, qd = Lf >> 4;
        const float4* src = (const float4*)(c + ((size_t)n * NS + (size_t)(kc * 4 + qd)) * ND);
        float4 a = src[0], bb = src[1];
        bf16x8 v;
        v[0] = (__bf16)a.x;  v[1] = (__bf16)a.y;  v[2] = (__bf16)a.z;  v[3] = (__bf16)a.w;
        v[4] = (__bf16)bb.x; v[5] = (__bf16)bb.y; v[6] = (__bf16)bb.z; v[7] = (__bf16)bb.w;
        *(bf16x8*)(Bf + (size_t)idx * 8) = v;
    }

    #pragma unroll
    for (int off = 32; off; off >>= 1) ss += __shfl_down(ss, off);
    if ((tid & 63) == 0) redn[tid >> 6] = ss;
    __syncthreads();                       // the ONE barrier before compute
    if (tid == 0) {
        float t = 0.f;
        #pragma unroll
        for (int i = 0; i < 16; ++i) t += redn[i];
        s_norm = sqrtf(t);
    }

    const int L    = tid & 63;
    const int m    = L & 15;       // A row within tile / D col (center id)
    const int quad = L >> 4;
    const int wu   = __builtin_amdgcn_readfirstlane(tid >> 6);  // wave 0..15

    // wave-uniform trapezoid window (all values multiples of 16)
    const int a0  = 112 - 16 * wu;
    const int klo = (a0 > 0) ? a0 : 0;                 // 112,96,...,16,0,0,...
    const int kh_ = (1022 - 64 * wu) >> 2;
    const int khi = (kh_ > 127) ? 127 : kh_;           // 127 x9, 111, ..., 15

    // A-frag (r,kc): 16B at gb + 32*(kc + 4r); ring slot (kc + 4r) & 15
    const __bf16* gb = xq + 8 * (64 * wu + m + quad);
    const __bf16* Bl = Bf + L * 8;

    bf16x8 Q[16];
    #pragma unroll
    for (int i = 0; i < 16; ++i) Q[i] = *(const bf16x8*)(gb + 32 * (klo + i));

    bf16x8 Bv[4];
    #pragma unroll
    for (int i = 0; i < 4; ++i) Bv[i] = *(const bf16x8*)(Bl + (size_t)(klo + i) * 512);

    floatx4 acc[4] = {};

    for (int kc0 = klo; kc0 <= khi; kc0 += 16) {
        #pragma unroll
        for (int s = 0; s < 16; ++s) {
            const int kc = kc0 + s;
            bf16x8 bcur = Bv[s & 3];
            acc[0] = MFMA(Q[(s + 0)  & 15], bcur, acc[0]);
            acc[1] = MFMA(Q[(s + 4)  & 15], bcur, acc[1]);
            acc[2] = MFMA(Q[(s + 8)  & 15], bcur, acc[2]);
            acc[3] = MFMA(Q[(s + 12) & 15], bcur, acc[3]);
            // slot s dead after r=0 use this iter; refill with row4 = kc+16
            Q[s & 15] = *(const bf16x8*)(gb + 32 * (kc + 16));
            // B lookahead 4 iters (~320cy); wrap &127 keeps reads in-bounds
            Bv[s & 3] = *(const bf16x8*)(Bl + (size_t)((kc + 4) & 127) * 512);
        }
    }

    // D layout: col = lane&15 (center), row-in-tile = quad*4 + e.
    // global lag row = 64wu + 16r + 4quad + e; phantom row 1023 excluded.
    float vmax = -INFINITY;
    #pragma unroll
    for (int r = 0; r < 4; ++r) {
        #pragma unroll
        for (int e = 0; e < 4; ++e) {
            bool phantom = (wu == 15) & (r == 3) & (quad == 3) & (e == 3);
            vmax = fmaxf(vmax, phantom ? -INFINITY : acc[r][e]);
        }
    }
    vmax = fmaxf(vmax, __shfl_xor(vmax, 16));
    vmax = fmaxf(vmax, __shfl_xor(vmax, 32));
    if (quad == 0) wred[wu][m] = vmax;
    __syncthreads();

    if (tid < 16) {
        float mm = wred[0][tid];
        #pragma unroll
        for (int i = 1; i < 16; ++i) mm = fmaxf(mm, wred[i][tid]);
        float denom = s_norm * (float)tid;
        float d = (denom < 1e-9f) ? 0.f : mm / denom;
        dd[tid] = d;
        out[NB + b * NK + tid] = d;
    }
    __syncthreads();
    if (tid == 0) {
        float best = dd[0]; int lab = 0;
        #pragma unroll
        for (int k = 1; k < NK; ++k) if (dd[k] > best) { best = dd[k]; lab = k; }
        out[b] = (float)lab;
    }
}

extern "C" void kernel_launch(void* const* d_in, const int* in_sizes, int n_in,
                              void* d_out, int out_size, void* d_ws, size_t ws_size,
                              hipStream_t stream) {
    const float* x = (const float*)d_in[0];
    const float* c = (const float*)d_in[1];
    float* out = (float*)d_out;
    kshape_kernel<<<NB, 1024, 0, stream>>>(x, c, out);
}